// Round 1
// baseline (2890.098 us; speedup 1.0000x reference)
//
#include <hip/hip_runtime.h>
#include <hip/hip_bf16.h>
#include <math.h>

#define CH 128
#define LAYERS 3
#define NEG_SLOPE 0.2f
#define EPS_D 1e-16f

__device__ __forceinline__ unsigned fmap(float f) {
    unsigned u = __float_as_uint(f);
    return (u & 0x80000000u) ? ~u : (u | 0x80000000u);
}
__device__ __forceinline__ float funmap(unsigned u) {
    unsigned v = (u & 0x80000000u) ? (u & 0x7fffffffu) : ~u;
    return __uint_as_float(v);
}
__device__ __forceinline__ float leaky(float e) { return e > 0.f ? e : NEG_SLOPE * e; }
__device__ __forceinline__ float sigm(float x) { return 1.f / (1.f + expf(-x)); }

// ---------------- GEMM: H = X @ W  (X: [n,128], W: [128,128] row-major k x c) ----------------
// 64 nodes per block, 256 threads, each thread 4 nodes x 8 channels.
__global__ __launch_bounds__(256) void gemm_k(const float* __restrict__ X,
                                              const float* __restrict__ Wm,
                                              float* __restrict__ H, int n) {
    __shared__ float Wl[128 * 128];   // 64 KB
    __shared__ float Xl[64][129];     // 33 KB, +1 pad breaks bank aliasing
    const int t = threadIdx.x;
    const int node0 = blockIdx.x * 64;

    // stage W (16384 floats) via float4
    const float4* W4 = (const float4*)Wm;
    float4* Wl4 = (float4*)Wl;
#pragma unroll
    for (int i = 0; i < 16; i++) Wl4[i * 256 + t] = W4[i * 256 + t];

    // stage X tile (64x128) via float4, scalar LDS writes (padded rows)
    const float4* X4 = (const float4*)X;
#pragma unroll
    for (int i = 0; i < 8; i++) {
        int flat4 = i * 256 + t;
        int r = flat4 >> 5, c4 = flat4 & 31;
        int node = node0 + r;
        float4 v = make_float4(0.f, 0.f, 0.f, 0.f);
        if (node < n) v = X4[(size_t)node * 32 + c4];
        Xl[r][c4 * 4 + 0] = v.x;
        Xl[r][c4 * 4 + 1] = v.y;
        Xl[r][c4 * 4 + 2] = v.z;
        Xl[r][c4 * 4 + 3] = v.w;
    }
    __syncthreads();

    const int tx = t & 15, ty = t >> 4;
    const int c0 = tx * 8, r0 = ty * 4;
    float acc[4][8];
#pragma unroll
    for (int j = 0; j < 4; j++)
#pragma unroll
        for (int i = 0; i < 8; i++) acc[j][i] = 0.f;

#pragma unroll 4
    for (int k = 0; k < 128; k++) {
        float xv[4];
#pragma unroll
        for (int j = 0; j < 4; j++) xv[j] = Xl[r0 + j][k];
        const float4 wa = *(const float4*)&Wl[k * 128 + c0];
        const float4 wb = *(const float4*)&Wl[k * 128 + c0 + 4];
        float wv[8] = {wa.x, wa.y, wa.z, wa.w, wb.x, wb.y, wb.z, wb.w};
#pragma unroll
        for (int j = 0; j < 4; j++)
#pragma unroll
            for (int i = 0; i < 8; i++) acc[j][i] += xv[j] * wv[i];
    }

#pragma unroll
    for (int j = 0; j < 4; j++) {
        int node = node0 + r0 + j;
        if (node < n) {
            float4 a = make_float4(acc[j][0], acc[j][1], acc[j][2], acc[j][3]);
            float4 b = make_float4(acc[j][4], acc[j][5], acc[j][6], acc[j][7]);
            *(float4*)&H[(size_t)node * CH + c0] = a;
            *(float4*)&H[(size_t)node * CH + c0 + 4] = b;
        }
    }
}

// ---------------- per-node attention scores: s = h.a_src, d = h.a_dst (wave per node) -------
__global__ __launch_bounds__(256) void sd_k(const float* __restrict__ H,
                                            const float* __restrict__ asrc,
                                            const float* __restrict__ adst,
                                            float* __restrict__ s, float* __restrict__ d, int n) {
    int g = blockIdx.x * 256 + threadIdx.x;
    int node = g >> 6;
    int lane = g & 63;
    if (node >= n) return;
    const float2 h2 = *(const float2*)&H[(size_t)node * CH + lane * 2];
    const float2 a2s = *(const float2*)&asrc[lane * 2];
    const float2 a2d = *(const float2*)&adst[lane * 2];
    float ps = h2.x * a2s.x + h2.y * a2s.y;
    float pd = h2.x * a2d.x + h2.y * a2d.y;
#pragma unroll
    for (int off = 32; off >= 1; off >>= 1) {
        ps += __shfl_down(ps, off);
        pd += __shfl_down(pd, off);
    }
    if (lane == 0) {
        s[node] = ps;
        d[node] = pd;
    }
}

// ---------------- init emax with self-loop edge value --------------------------------------
__global__ void init_node_k(const float* __restrict__ s, const float* __restrict__ d,
                            unsigned* __restrict__ emax_u, int n) {
    int i = blockIdx.x * 256 + threadIdx.x;
    if (i >= n) return;
    emax_u[i] = fmap(leaky(s[i] + d[i]));
}

// ---------------- edge pass 1: segment max ---------------------------------------------------
__global__ void edge_max_k(const int* __restrict__ EI, const float* __restrict__ s,
                           const float* __restrict__ d, unsigned* __restrict__ emax_u, int ne) {
    int e = blockIdx.x * 256 + threadIdx.x;
    if (e >= ne) return;
    int src = EI[e], dst = EI[ne + e];
    float ev = leaky(s[src] + d[dst]);
    atomicMax(&emax_u[dst], fmap(ev));
}

// ---------------- init denom with self-loop contribution ------------------------------------
__global__ void init_denom_k(const float* __restrict__ s, const float* __restrict__ d,
                             const unsigned* __restrict__ emax_u, float* __restrict__ denom, int n) {
    int i = blockIdx.x * 256 + threadIdx.x;
    if (i >= n) return;
    float es = leaky(s[i] + d[i]);
    denom[i] = expf(es - funmap(emax_u[i]));
}

// ---------------- edge pass 2: segment sum of exp -------------------------------------------
__global__ void edge_sum_k(const int* __restrict__ EI, const float* __restrict__ s,
                           const float* __restrict__ d, const unsigned* __restrict__ emax_u,
                           float* __restrict__ denom, int ne) {
    int e = blockIdx.x * 256 + threadIdx.x;
    if (e >= ne) return;
    int src = EI[e], dst = EI[ne + e];
    float ev = leaky(s[src] + d[dst]);
    float w = expf(ev - funmap(emax_u[dst]));
    atomicAdd(&denom[dst], w);
}

// ---------------- init out with self-loop contribution (elementwise over n*128) -------------
__global__ void init_out_k(const float* __restrict__ s, const float* __restrict__ d,
                           const unsigned* __restrict__ emax_u, const float* __restrict__ denom,
                           const float* __restrict__ H, float* __restrict__ out, long total) {
    long idx = (long)blockIdx.x * 256 + threadIdx.x;
    if (idx >= total) return;
    int i = (int)(idx >> 7);
    float es = leaky(s[i] + d[i]);
    float alpha = expf(es - funmap(emax_u[i])) / (denom[i] + EPS_D);
    out[idx] = alpha * H[idx];
}

// ---------------- edge pass 3: aggregate alpha * h[src] into out[dst] (wave per edge) -------
__global__ __launch_bounds__(256) void edge_aggr_k(const int* __restrict__ EI,
                                                   const float* __restrict__ s,
                                                   const float* __restrict__ d,
                                                   const unsigned* __restrict__ emax_u,
                                                   const float* __restrict__ denom,
                                                   const float* __restrict__ H,
                                                   float* __restrict__ out, int ne) {
    long g = (long)blockIdx.x * 256 + threadIdx.x;
    int e = (int)(g >> 6);
    int lane = (int)(g & 63);
    if (e >= ne) return;
    int src = EI[e], dst = EI[ne + e];
    float ev = leaky(s[src] + d[dst]);
    float w = expf(ev - funmap(emax_u[dst]));
    float alpha = w / (denom[dst] + EPS_D);
    const float* hr = H + (size_t)src * CH;
    float* orow = out + (size_t)dst * CH;
    atomicAdd(&orow[lane], alpha * hr[lane]);
    atomicAdd(&orow[lane + 64], alpha * hr[lane + 64]);
}

// ---------------- residual update: x = x + sigmoid(out + b) ---------------------------------
__global__ void update_k(const float* __restrict__ out, const float* __restrict__ bias,
                         float* __restrict__ x_cur, float* __restrict__ final_out,
                         int is_last, long total) {
    long idx = (long)blockIdx.x * 256 + threadIdx.x;
    if (idx >= total) return;
    int c = (int)(idx & 127);
    float v = x_cur[idx] + sigm(out[idx] + bias[c]);
    x_cur[idx] = v;
    if (is_last) final_out[idx] = v;
}

extern "C" void kernel_launch(void* const* d_in, const int* in_sizes, int n_in,
                              void* d_out, int out_size, void* d_ws, size_t ws_size,
                              hipStream_t stream) {
    const float* x_in = (const float*)d_in[0];
    const int* EI = (const int*)d_in[1];
    const float* Ws_all = (const float*)d_in[2];
    const float* asrc_all = (const float*)d_in[3];
    const float* adst_all = (const float*)d_in[4];
    const float* bias_all = (const float*)d_in[5];
    float* out = (float*)d_out;

    const int n = in_sizes[0] / CH;        // 100000
    const int ne = in_sizes[1] / 2;        // 1600000
    const long NC = (long)n * CH;

    float* x_cur = (float*)d_ws;
    float* h = x_cur + NC;
    float* s = h + NC;
    float* dd = s + n;
    unsigned* emax_u = (unsigned*)(dd + n);
    float* denom = (float*)(emax_u + n);

    hipMemcpyAsync(x_cur, x_in, NC * sizeof(float), hipMemcpyDeviceToDevice, stream);

    const int gN = (n + 255) / 256;
    const int gE = (ne + 255) / 256;
    const int gNC = (int)((NC + 255) / 256);

    for (int m = 0; m < LAYERS; m++) {
        const float* Wm = Ws_all + (size_t)m * CH * CH;
        const float* as = asrc_all + (size_t)m * CH;
        const float* ad = adst_all + (size_t)m * CH;
        const float* bm = bias_all + (size_t)m * CH;

        gemm_k<<<(n + 63) / 64, 256, 0, stream>>>(x_cur, Wm, h, n);
        sd_k<<<(n + 3) / 4, 256, 0, stream>>>(h, as, ad, s, dd, n);
        init_node_k<<<gN, 256, 0, stream>>>(s, dd, emax_u, n);
        edge_max_k<<<gE, 256, 0, stream>>>(EI, s, dd, emax_u, ne);
        init_denom_k<<<gN, 256, 0, stream>>>(s, dd, emax_u, denom, n);
        edge_sum_k<<<gE, 256, 0, stream>>>(EI, s, dd, emax_u, denom, ne);
        init_out_k<<<gNC, 256, 0, stream>>>(s, dd, emax_u, denom, h, out, NC);
        edge_aggr_k<<<(ne + 3) / 4, 256, 0, stream>>>(EI, s, dd, emax_u, denom, h, out, ne);
        update_k<<<gNC, 256, 0, stream>>>(out, bm, x_cur, out, m == LAYERS - 1, NC);
    }
}

// Round 2
// 1063.102 us; speedup vs baseline: 2.7186x; 2.7186x over previous
//
#include <hip/hip_runtime.h>
#include <hip/hip_bf16.h>
#include <math.h>

#define CH 128
#define LAYERS 3
#define NEG_SLOPE 0.2f
#define EPS_D 1e-16f

__device__ __forceinline__ float leaky(float e) { return e > 0.f ? e : NEG_SLOPE * e; }
__device__ __forceinline__ float sigm(float x) { return 1.f / (1.f + __expf(-x)); }

// ---------------- CSR build -----------------------------------------------------------------
__global__ void deg_k(const int* __restrict__ EI, int* __restrict__ deg, int ne) {
    int e = blockIdx.x * 256 + threadIdx.x;
    if (e >= ne) return;
    atomicAdd(&deg[EI[ne + e]], 1);
}

// single-block exclusive scan over deg -> rowptr (n+1) and cursor copy
__global__ __launch_bounds__(1024) void scan_k(const int* __restrict__ deg,
                                               int* __restrict__ rowptr,
                                               int* __restrict__ cursor, int n) {
    __shared__ int lds[1024];
    __shared__ int s_carry;
    const int t = threadIdx.x;
    if (t == 0) s_carry = 0;
    __syncthreads();
    for (int base = 0; base < n; base += 1024) {
        int idx = base + t;
        int v = (idx < n) ? deg[idx] : 0;
        lds[t] = v;
        __syncthreads();
        for (int off = 1; off < 1024; off <<= 1) {
            int x = (t >= off) ? lds[t - off] : 0;
            __syncthreads();
            lds[t] += x;
            __syncthreads();
        }
        int excl = lds[t] - v;
        if (idx < n) {
            int val = s_carry + excl;
            rowptr[idx] = val;
            cursor[idx] = val;
        }
        __syncthreads();
        if (t == 1023) s_carry += lds[1023];
        __syncthreads();
    }
    if (t == 0) rowptr[n] = s_carry;
}

__global__ void scatter_k(const int* __restrict__ EI, int* __restrict__ cursor,
                          int* __restrict__ col, int ne) {
    int e = blockIdx.x * 256 + threadIdx.x;
    if (e >= ne) return;
    int src = EI[e], dst = EI[ne + e];
    int pos = atomicAdd(&cursor[dst], 1);
    col[pos] = src;
}

// ---------------- GEMM: H = X @ W, fused s = H.a_src, d = H.a_dst ---------------------------
// 64 nodes per block, 256 threads, each thread 4 nodes x 8 channels.
__global__ __launch_bounds__(256) void gemm_k(const float* __restrict__ X,
                                              const float* __restrict__ Wm,
                                              const float* __restrict__ asrc,
                                              const float* __restrict__ adst,
                                              float* __restrict__ H,
                                              float* __restrict__ s,
                                              float* __restrict__ d, int n) {
    __shared__ float Wl[128 * 128];   // 64 KB
    __shared__ float Xl[64][129];     // 33 KB
    const int t = threadIdx.x;
    const int node0 = blockIdx.x * 64;

    const float4* W4 = (const float4*)Wm;
    float4* Wl4 = (float4*)Wl;
#pragma unroll
    for (int i = 0; i < 16; i++) Wl4[i * 256 + t] = W4[i * 256 + t];

    const float4* X4 = (const float4*)X;
#pragma unroll
    for (int i = 0; i < 8; i++) {
        int flat4 = i * 256 + t;
        int r = flat4 >> 5, c4 = flat4 & 31;
        int node = node0 + r;
        float4 v = make_float4(0.f, 0.f, 0.f, 0.f);
        if (node < n) v = X4[(size_t)node * 32 + c4];
        Xl[r][c4 * 4 + 0] = v.x;
        Xl[r][c4 * 4 + 1] = v.y;
        Xl[r][c4 * 4 + 2] = v.z;
        Xl[r][c4 * 4 + 3] = v.w;
    }
    __syncthreads();

    const int tx = t & 15, ty = t >> 4;
    const int c0 = tx * 8, r0 = ty * 4;
    float acc[4][8];
#pragma unroll
    for (int j = 0; j < 4; j++)
#pragma unroll
        for (int i = 0; i < 8; i++) acc[j][i] = 0.f;

#pragma unroll 4
    for (int k = 0; k < 128; k++) {
        float xv[4];
#pragma unroll
        for (int j = 0; j < 4; j++) xv[j] = Xl[r0 + j][k];
        const float4 wa = *(const float4*)&Wl[k * 128 + c0];
        const float4 wb = *(const float4*)&Wl[k * 128 + c0 + 4];
        float wv[8] = {wa.x, wa.y, wa.z, wa.w, wb.x, wb.y, wb.z, wb.w};
#pragma unroll
        for (int j = 0; j < 4; j++)
#pragma unroll
            for (int i = 0; i < 8; i++) acc[j][i] += xv[j] * wv[i];
    }

    float as8[8], ad8[8];
#pragma unroll
    for (int i = 0; i < 8; i++) { as8[i] = asrc[c0 + i]; ad8[i] = adst[c0 + i]; }

#pragma unroll
    for (int j = 0; j < 4; j++) {
        int node = node0 + r0 + j;
        if (node < n) {
            float4 a = make_float4(acc[j][0], acc[j][1], acc[j][2], acc[j][3]);
            float4 b = make_float4(acc[j][4], acc[j][5], acc[j][6], acc[j][7]);
            *(float4*)&H[(size_t)node * CH + c0] = a;
            *(float4*)&H[(size_t)node * CH + c0 + 4] = b;
        }
        float ps = 0.f, pd = 0.f;
#pragma unroll
        for (int i = 0; i < 8; i++) { ps += acc[j][i] * as8[i]; pd += acc[j][i] * ad8[i]; }
#pragma unroll
        for (int off = 8; off >= 1; off >>= 1) {
            ps += __shfl_xor(ps, off);
            pd += __shfl_xor(pd, off);
        }
        if (tx == 0 && node < n) { s[node] = ps; d[node] = pd; }
    }
}

// ---------------- per-node softmax + aggregation + residual update (wave per node) ----------
__global__ __launch_bounds__(256) void node_aggr_k(const int* __restrict__ rowptr,
                                                   const int* __restrict__ col,
                                                   const float* __restrict__ s,
                                                   const float* __restrict__ d,
                                                   const float* __restrict__ H,
                                                   const float* __restrict__ bias,
                                                   const float* __restrict__ x_prev,
                                                   float* __restrict__ x_next, int n) {
    long g = (long)blockIdx.x * 256 + threadIdx.x;
    int node = (int)(g >> 6);
    int lane = (int)(g & 63);
    if (node >= n) return;

    const int beg = rowptr[node], end = rowptr[node + 1];
    const float dn = d[node];
    const float ev_self = leaky(s[node] + dn);

    // phase 1: segment max (lanes parallel over edges)
    float m = ev_self;
    for (int j = beg + lane; j < end; j += 64) {
        m = fmaxf(m, leaky(s[col[j]] + dn));
    }
#pragma unroll
    for (int off = 32; off >= 1; off >>= 1) m = fmaxf(m, __shfl_xor(m, off));

    // phase 2: weights + gather-accumulate (2 channels per lane)
    float l = 0.f, o0 = 0.f, o1 = 0.f;
    for (int j0 = beg; j0 < end; j0 += 64) {
        int cnt = min(64, end - j0);
        int srcv = 0;
        float wv = 0.f;
        if (lane < cnt) {
            srcv = col[j0 + lane];
            wv = __expf(leaky(s[srcv] + dn) - m);
        }
        for (int i = 0; i < cnt; i++) {
            int src = __shfl(srcv, i);
            float w = __shfl(wv, i);
            const float2 h2 = *(const float2*)&H[(size_t)src * CH + lane * 2];
            l += w;
            o0 += w * h2.x;
            o1 += w * h2.y;
        }
    }
    // self loop
    float wself = __expf(ev_self - m);
    l += wself;
    const float2 hs = *(const float2*)&H[(size_t)node * CH + lane * 2];
    o0 += wself * hs.x;
    o1 += wself * hs.y;

    float inv = 1.f / (l + EPS_D);
    const float2 xv = *(const float2*)&x_prev[(size_t)node * CH + lane * 2];
    float b0 = bias[lane * 2], b1 = bias[lane * 2 + 1];
    float r0 = xv.x + sigm(o0 * inv + b0);
    float r1 = xv.y + sigm(o1 * inv + b1);
    *(float2*)&x_next[(size_t)node * CH + lane * 2] = make_float2(r0, r1);
}

extern "C" void kernel_launch(void* const* d_in, const int* in_sizes, int n_in,
                              void* d_out, int out_size, void* d_ws, size_t ws_size,
                              hipStream_t stream) {
    const float* x_in = (const float*)d_in[0];
    const int* EI = (const int*)d_in[1];
    const float* Ws_all = (const float*)d_in[2];
    const float* asrc_all = (const float*)d_in[3];
    const float* adst_all = (const float*)d_in[4];
    const float* bias_all = (const float*)d_in[5];
    float* out = (float*)d_out;

    const int n = in_sizes[0] / CH;        // 100000
    const int ne = in_sizes[1] / 2;        // 1600000
    const long NC = (long)n * CH;

    float* h = (float*)d_ws;
    float* s = h + NC;
    float* dd = s + n;
    float* x_ws = dd + n;
    int* rowptr = (int*)(x_ws + NC);
    int* deg = rowptr + (n + 1);           // reused as scatter cursor
    int* colv = deg + n;

    // --- CSR build (dst-grouped) ---
    hipMemsetAsync(deg, 0, (size_t)n * sizeof(int), stream);
    deg_k<<<(ne + 255) / 256, 256, 0, stream>>>(EI, deg, ne);
    scan_k<<<1, 1024, 0, stream>>>(deg, rowptr, deg, n);   // deg becomes cursor
    scatter_k<<<(ne + 255) / 256, 256, 0, stream>>>(EI, deg, colv, ne);

    // layer m: x_prev -> x_next;  chain: x_in -> out -> x_ws -> out
    const float* xp[LAYERS] = {x_in, out, x_ws};
    float* xn[LAYERS] = {out, x_ws, out};

    for (int m = 0; m < LAYERS; m++) {
        const float* Wm = Ws_all + (size_t)m * CH * CH;
        const float* as = asrc_all + (size_t)m * CH;
        const float* ad = adst_all + (size_t)m * CH;
        const float* bm = bias_all + (size_t)m * CH;

        gemm_k<<<(n + 63) / 64, 256, 0, stream>>>(xp[m], Wm, as, ad, h, s, dd, n);
        node_aggr_k<<<(n * 64 + 255) / 256, 256, 0, stream>>>(rowptr, colv, s, dd, h, bm,
                                                              xp[m], xn[m], n);
    }
}

// Round 3
// 894.342 us; speedup vs baseline: 3.2315x; 1.1887x over previous
//
#include <hip/hip_runtime.h>
#include <hip/hip_bf16.h>
#include <math.h>

#define CH 128
#define LAYERS 3
#define NEG_SLOPE 0.2f
#define EPS_D 1e-16f

__device__ __forceinline__ float leaky(float e) { return e > 0.f ? e : NEG_SLOPE * e; }
__device__ __forceinline__ float sigm(float x) { return 1.f / (1.f + __expf(-x)); }

// ---------------- CSR build -----------------------------------------------------------------
__global__ void deg_k(const int* __restrict__ EI, int* __restrict__ deg, int ne) {
    int e = blockIdx.x * 256 + threadIdx.x;
    if (e >= ne) return;
    atomicAdd(&deg[EI[ne + e]], 1);
}

// step 1: per-block exclusive scan (1024 elems/block) -> rowptr(local), blocksum
__global__ __launch_bounds__(1024) void partial_scan_k(const int* __restrict__ deg,
                                                       int* __restrict__ rowptr,
                                                       int* __restrict__ blocksum, int n) {
    __shared__ int wsum[16];
    const int t = threadIdx.x;
    const int lane = t & 63, w = t >> 6;
    const int idx = blockIdx.x * 1024 + t;
    int v = (idx < n) ? deg[idx] : 0;
    int sc = v;
#pragma unroll
    for (int off = 1; off < 64; off <<= 1) {
        int x = __shfl_up(sc, off);
        if (lane >= off) sc += x;
    }
    if (lane == 63) wsum[w] = sc;
    __syncthreads();
    if (w == 0) {
        int ws = (lane < 16) ? wsum[lane] : 0;
#pragma unroll
        for (int off = 1; off < 16; off <<= 1) {
            int x = __shfl_up(ws, off);
            if (lane >= off) ws += x;
        }
        if (lane < 16) wsum[lane] = ws;
    }
    __syncthreads();
    int excl = sc - v + (w > 0 ? wsum[w - 1] : 0);
    if (idx < n) rowptr[idx] = excl;
    if (t == 1023) blocksum[blockIdx.x] = excl + v;
}

// step 2: one wave scans block totals (nb ~ 98) -> blockoff (exclusive), rowptr[n] = total
__global__ __launch_bounds__(64) void blockscan_k(const int* __restrict__ blocksum,
                                                  int* __restrict__ blockoff,
                                                  int* __restrict__ rowptr, int nb, int n) {
    const int lane = threadIdx.x;
    int carry = 0;
    for (int base = 0; base < nb; base += 64) {
        int v = (base + lane < nb) ? blocksum[base + lane] : 0;
        int sc = v;
#pragma unroll
        for (int off = 1; off < 64; off <<= 1) {
            int x = __shfl_up(sc, off);
            if (lane >= off) sc += x;
        }
        if (base + lane < nb) blockoff[base + lane] = carry + sc - v;
        carry += __shfl(sc, 63);
    }
    if (lane == 0) rowptr[n] = carry;
}

// step 3: add block offsets; produce final rowptr + cursor copy
__global__ void add_off_k(int* __restrict__ rowptr, const int* __restrict__ blockoff,
                          int* __restrict__ cursor, int n) {
    int idx = blockIdx.x * 256 + threadIdx.x;
    if (idx >= n) return;
    int val = rowptr[idx] + blockoff[idx >> 10];
    rowptr[idx] = val;
    cursor[idx] = val;
}

__global__ void scatter_k(const int* __restrict__ EI, int* __restrict__ cursor,
                          int* __restrict__ col, int ne) {
    int e = blockIdx.x * 256 + threadIdx.x;
    if (e >= ne) return;
    int src = EI[e], dst = EI[ne + e];
    int pos = atomicAdd(&cursor[dst], 1);
    col[pos] = src;
}

// ---------------- GEMM: H = X @ W, fused s = H.a_src, d = H.a_dst ---------------------------
__global__ __launch_bounds__(256) void gemm_k(const float* __restrict__ X,
                                              const float* __restrict__ Wm,
                                              const float* __restrict__ asrc,
                                              const float* __restrict__ adst,
                                              float* __restrict__ H,
                                              float* __restrict__ s,
                                              float* __restrict__ d, int n) {
    __shared__ float Wl[128 * 128];   // 64 KB
    __shared__ float Xl[64][129];     // 33 KB
    const int t = threadIdx.x;
    const int node0 = blockIdx.x * 64;

    const float4* W4 = (const float4*)Wm;
    float4* Wl4 = (float4*)Wl;
#pragma unroll
    for (int i = 0; i < 16; i++) Wl4[i * 256 + t] = W4[i * 256 + t];

    const float4* X4 = (const float4*)X;
#pragma unroll
    for (int i = 0; i < 8; i++) {
        int flat4 = i * 256 + t;
        int r = flat4 >> 5, c4 = flat4 & 31;
        int node = node0 + r;
        float4 v = make_float4(0.f, 0.f, 0.f, 0.f);
        if (node < n) v = X4[(size_t)node * 32 + c4];
        Xl[r][c4 * 4 + 0] = v.x;
        Xl[r][c4 * 4 + 1] = v.y;
        Xl[r][c4 * 4 + 2] = v.z;
        Xl[r][c4 * 4 + 3] = v.w;
    }
    __syncthreads();

    const int tx = t & 15, ty = t >> 4;
    const int c0 = tx * 8, r0 = ty * 4;
    float acc[4][8];
#pragma unroll
    for (int j = 0; j < 4; j++)
#pragma unroll
        for (int i = 0; i < 8; i++) acc[j][i] = 0.f;

#pragma unroll 4
    for (int k = 0; k < 128; k++) {
        float xv[4];
#pragma unroll
        for (int j = 0; j < 4; j++) xv[j] = Xl[r0 + j][k];
        const float4 wa = *(const float4*)&Wl[k * 128 + c0];
        const float4 wb = *(const float4*)&Wl[k * 128 + c0 + 4];
        float wv[8] = {wa.x, wa.y, wa.z, wa.w, wb.x, wb.y, wb.z, wb.w};
#pragma unroll
        for (int j = 0; j < 4; j++)
#pragma unroll
            for (int i = 0; i < 8; i++) acc[j][i] += xv[j] * wv[i];
    }

    float as8[8], ad8[8];
#pragma unroll
    for (int i = 0; i < 8; i++) { as8[i] = asrc[c0 + i]; ad8[i] = adst[c0 + i]; }

#pragma unroll
    for (int j = 0; j < 4; j++) {
        int node = node0 + r0 + j;
        if (node < n) {
            float4 a = make_float4(acc[j][0], acc[j][1], acc[j][2], acc[j][3]);
            float4 b = make_float4(acc[j][4], acc[j][5], acc[j][6], acc[j][7]);
            *(float4*)&H[(size_t)node * CH + c0] = a;
            *(float4*)&H[(size_t)node * CH + c0 + 4] = b;
        }
        float ps = 0.f, pd = 0.f;
#pragma unroll
        for (int i = 0; i < 8; i++) { ps += acc[j][i] * as8[i]; pd += acc[j][i] * ad8[i]; }
#pragma unroll
        for (int off = 8; off >= 1; off >>= 1) {
            ps += __shfl_xor(ps, off);
            pd += __shfl_xor(pd, off);
        }
        if (tx == 0 && node < n) { s[node] = ps; d[node] = pd; }
    }
}

// ---------------- per-node softmax + aggregation + residual update (wave per node) ----------
__global__ __launch_bounds__(256) void node_aggr_k(const int* __restrict__ rowptr,
                                                   const int* __restrict__ col,
                                                   const float* __restrict__ s,
                                                   const float* __restrict__ d,
                                                   const float* __restrict__ H,
                                                   const float* __restrict__ bias,
                                                   const float* __restrict__ x_prev,
                                                   float* __restrict__ x_next, int n) {
    long g = (long)blockIdx.x * 256 + threadIdx.x;
    int node = (int)(g >> 6);
    int lane = (int)(g & 63);
    if (node >= n) return;

    const int beg = rowptr[node], end = rowptr[node + 1];
    const float dn = d[node];
    const float ev_self = leaky(s[node] + dn);

    float m = ev_self;
    for (int j = beg + lane; j < end; j += 64) {
        m = fmaxf(m, leaky(s[col[j]] + dn));
    }
#pragma unroll
    for (int off = 32; off >= 1; off >>= 1) m = fmaxf(m, __shfl_xor(m, off));

    float l = 0.f, o0 = 0.f, o1 = 0.f;
    for (int j0 = beg; j0 < end; j0 += 64) {
        int cnt = min(64, end - j0);
        int srcv = 0;
        float wv = 0.f;
        if (lane < cnt) {
            srcv = col[j0 + lane];
            wv = __expf(leaky(s[srcv] + dn) - m);
        }
        for (int i = 0; i < cnt; i++) {
            int src = __shfl(srcv, i);
            float w = __shfl(wv, i);
            const float2 h2 = *(const float2*)&H[(size_t)src * CH + lane * 2];
            l += w;
            o0 += w * h2.x;
            o1 += w * h2.y;
        }
    }
    float wself = __expf(ev_self - m);
    l += wself;
    const float2 hs = *(const float2*)&H[(size_t)node * CH + lane * 2];
    o0 += wself * hs.x;
    o1 += wself * hs.y;

    float inv = 1.f / (l + EPS_D);
    const float2 xv = *(const float2*)&x_prev[(size_t)node * CH + lane * 2];
    float b0 = bias[lane * 2], b1 = bias[lane * 2 + 1];
    float r0 = xv.x + sigm(o0 * inv + b0);
    float r1 = xv.y + sigm(o1 * inv + b1);
    *(float2*)&x_next[(size_t)node * CH + lane * 2] = make_float2(r0, r1);
}

extern "C" void kernel_launch(void* const* d_in, const int* in_sizes, int n_in,
                              void* d_out, int out_size, void* d_ws, size_t ws_size,
                              hipStream_t stream) {
    const float* x_in = (const float*)d_in[0];
    const int* EI = (const int*)d_in[1];
    const float* Ws_all = (const float*)d_in[2];
    const float* asrc_all = (const float*)d_in[3];
    const float* adst_all = (const float*)d_in[4];
    const float* bias_all = (const float*)d_in[5];
    float* out = (float*)d_out;

    const int n = in_sizes[0] / CH;        // 100000
    const int ne = in_sizes[1] / 2;        // 1600000
    const long NC = (long)n * CH;
    const int nb = (n + 1023) / 1024;

    float* h = (float*)d_ws;
    float* s = h + NC;
    float* dd = s + n;
    float* x_ws = dd + n;
    int* rowptr = (int*)(x_ws + NC);
    int* deg = rowptr + (n + 1);           // reused as scatter cursor
    int* blocksum = deg + n;
    int* blockoff = blocksum + nb;
    int* colv = blockoff + nb;

    // --- CSR build (dst-grouped) ---
    hipMemsetAsync(deg, 0, (size_t)n * sizeof(int), stream);
    deg_k<<<(ne + 255) / 256, 256, 0, stream>>>(EI, deg, ne);
    partial_scan_k<<<nb, 1024, 0, stream>>>(deg, rowptr, blocksum, n);
    blockscan_k<<<1, 64, 0, stream>>>(blocksum, blockoff, rowptr, nb, n);
    add_off_k<<<(n + 255) / 256, 256, 0, stream>>>(rowptr, blockoff, deg, n);  // deg -> cursor
    scatter_k<<<(ne + 255) / 256, 256, 0, stream>>>(EI, deg, colv, ne);

    const float* xp[LAYERS] = {x_in, out, x_ws};
    float* xn[LAYERS] = {out, x_ws, out};

    for (int m = 0; m < LAYERS; m++) {
        const float* Wm = Ws_all + (size_t)m * CH * CH;
        const float* as = asrc_all + (size_t)m * CH;
        const float* ad = adst_all + (size_t)m * CH;
        const float* bm = bias_all + (size_t)m * CH;

        gemm_k<<<(n + 63) / 64, 256, 0, stream>>>(xp[m], Wm, as, ad, h, s, dd, n);
        node_aggr_k<<<(n * 64 + 255) / 256, 256, 0, stream>>>(rowptr, colv, s, dd, h, bm,
                                                              xp[m], xn[m], n);
    }
}

// Round 4
// 824.806 us; speedup vs baseline: 3.5040x; 1.0843x over previous
//
#include <hip/hip_runtime.h>
#include <hip/hip_bf16.h>
#include <math.h>

#define CH 128
#define LAYERS 3
#define NEG_SLOPE 0.2f
#define EPS_D 1e-16f

__device__ __forceinline__ float leaky(float e) { return e > 0.f ? e : NEG_SLOPE * e; }
__device__ __forceinline__ float sigm(float x) { return 1.f / (1.f + __expf(-x)); }

// round-to-nearest-even f32 -> bf16 (bits in low 16)
__device__ __forceinline__ unsigned bf16rne(float f) {
    unsigned u = __float_as_uint(f);
    return (u + 0x7fffu + ((u >> 16) & 1u)) >> 16;
}
__device__ __forceinline__ unsigned pack2(float f0, float f1) {
    return bf16rne(f0) | (bf16rne(f1) << 16);
}
__device__ __forceinline__ float bflo(unsigned u) { return __uint_as_float(u << 16); }
__device__ __forceinline__ float bfhi(unsigned u) { return __uint_as_float(u & 0xffff0000u); }

// ---------------- CSR build -----------------------------------------------------------------
__global__ void deg_k(const int* __restrict__ EI, int* __restrict__ deg, int ne) {
    int e = blockIdx.x * 256 + threadIdx.x;
    if (e >= ne) return;
    atomicAdd(&deg[EI[ne + e]], 1);
}

__global__ __launch_bounds__(1024) void partial_scan_k(const int* __restrict__ deg,
                                                       int* __restrict__ rowptr,
                                                       int* __restrict__ blocksum, int n) {
    __shared__ int wsum[16];
    const int t = threadIdx.x;
    const int lane = t & 63, w = t >> 6;
    const int idx = blockIdx.x * 1024 + t;
    int v = (idx < n) ? deg[idx] : 0;
    int sc = v;
#pragma unroll
    for (int off = 1; off < 64; off <<= 1) {
        int x = __shfl_up(sc, off);
        if (lane >= off) sc += x;
    }
    if (lane == 63) wsum[w] = sc;
    __syncthreads();
    if (w == 0) {
        int ws = (lane < 16) ? wsum[lane] : 0;
#pragma unroll
        for (int off = 1; off < 16; off <<= 1) {
            int x = __shfl_up(ws, off);
            if (lane >= off) ws += x;
        }
        if (lane < 16) wsum[lane] = ws;
    }
    __syncthreads();
    int excl = sc - v + (w > 0 ? wsum[w - 1] : 0);
    if (idx < n) rowptr[idx] = excl;
    if (t == 1023) blocksum[blockIdx.x] = excl + v;
}

__global__ __launch_bounds__(64) void blockscan_k(const int* __restrict__ blocksum,
                                                  int* __restrict__ blockoff,
                                                  int* __restrict__ rowptr, int nb, int n) {
    const int lane = threadIdx.x;
    int carry = 0;
    for (int base = 0; base < nb; base += 64) {
        int v = (base + lane < nb) ? blocksum[base + lane] : 0;
        int sc = v;
#pragma unroll
        for (int off = 1; off < 64; off <<= 1) {
            int x = __shfl_up(sc, off);
            if (lane >= off) sc += x;
        }
        if (base + lane < nb) blockoff[base + lane] = carry + sc - v;
        carry += __shfl(sc, 63);
    }
    if (lane == 0) rowptr[n] = carry;
}

__global__ void add_off_k(int* __restrict__ rowptr, const int* __restrict__ blockoff,
                          int* __restrict__ cursor, int n) {
    int idx = blockIdx.x * 256 + threadIdx.x;
    if (idx >= n) return;
    int val = rowptr[idx] + blockoff[idx >> 10];
    rowptr[idx] = val;
    cursor[idx] = val;
}

__global__ void scatter_k(const int* __restrict__ EI, int* __restrict__ cursor,
                          int* __restrict__ col, int ne) {
    int e = blockIdx.x * 256 + threadIdx.x;
    if (e >= ne) return;
    int src = EI[e], dst = EI[ne + e];
    int pos = atomicAdd(&cursor[dst], 1);
    col[pos] = src;
}

// ---------------- GEMM: H(bf16) = X @ W, fused s = H.a_src, d = H.a_dst ---------------------
__global__ __launch_bounds__(256) void gemm_k(const float* __restrict__ X,
                                              const float* __restrict__ Wm,
                                              const float* __restrict__ asrc,
                                              const float* __restrict__ adst,
                                              unsigned* __restrict__ Hb,
                                              float* __restrict__ s,
                                              float* __restrict__ d, int n) {
    __shared__ float Wl[128 * 128];   // 64 KB
    __shared__ float Xl[64][129];     // 33 KB
    const int t = threadIdx.x;
    const int node0 = blockIdx.x * 64;

    const float4* W4 = (const float4*)Wm;
    float4* Wl4 = (float4*)Wl;
#pragma unroll
    for (int i = 0; i < 16; i++) Wl4[i * 256 + t] = W4[i * 256 + t];

    const float4* X4 = (const float4*)X;
#pragma unroll
    for (int i = 0; i < 8; i++) {
        int flat4 = i * 256 + t;
        int r = flat4 >> 5, c4 = flat4 & 31;
        int node = node0 + r;
        float4 v = make_float4(0.f, 0.f, 0.f, 0.f);
        if (node < n) v = X4[(size_t)node * 32 + c4];
        Xl[r][c4 * 4 + 0] = v.x;
        Xl[r][c4 * 4 + 1] = v.y;
        Xl[r][c4 * 4 + 2] = v.z;
        Xl[r][c4 * 4 + 3] = v.w;
    }
    __syncthreads();

    const int tx = t & 15, ty = t >> 4;
    const int c0 = tx * 8, r0 = ty * 4;
    float acc[4][8];
#pragma unroll
    for (int j = 0; j < 4; j++)
#pragma unroll
        for (int i = 0; i < 8; i++) acc[j][i] = 0.f;

#pragma unroll 4
    for (int k = 0; k < 128; k++) {
        float xv[4];
#pragma unroll
        for (int j = 0; j < 4; j++) xv[j] = Xl[r0 + j][k];
        const float4 wa = *(const float4*)&Wl[k * 128 + c0];
        const float4 wb = *(const float4*)&Wl[k * 128 + c0 + 4];
        float wv[8] = {wa.x, wa.y, wa.z, wa.w, wb.x, wb.y, wb.z, wb.w};
#pragma unroll
        for (int j = 0; j < 4; j++)
#pragma unroll
            for (int i = 0; i < 8; i++) acc[j][i] += xv[j] * wv[i];
    }

    float as8[8], ad8[8];
#pragma unroll
    for (int i = 0; i < 8; i++) { as8[i] = asrc[c0 + i]; ad8[i] = adst[c0 + i]; }

#pragma unroll
    for (int j = 0; j < 4; j++) {
        int node = node0 + r0 + j;
        if (node < n) {
            uint4 p;
            p.x = pack2(acc[j][0], acc[j][1]);
            p.y = pack2(acc[j][2], acc[j][3]);
            p.z = pack2(acc[j][4], acc[j][5]);
            p.w = pack2(acc[j][6], acc[j][7]);
            *(uint4*)&Hb[(size_t)node * 64 + tx * 4] = p;
        }
        float ps = 0.f, pd = 0.f;
#pragma unroll
        for (int i = 0; i < 8; i++) { ps += acc[j][i] * as8[i]; pd += acc[j][i] * ad8[i]; }
#pragma unroll
        for (int off = 8; off >= 1; off >>= 1) {
            ps += __shfl_xor(ps, off);
            pd += __shfl_xor(pd, off);
        }
        if (tx == 0 && node < n) { s[node] = ps; d[node] = pd; }
    }
}

// ---------------- per-node online-softmax + aggregation + residual (wave per node) ----------
__global__ __launch_bounds__(256) void node_aggr_k(const int* __restrict__ rowptr,
                                                   const int* __restrict__ col,
                                                   const float* __restrict__ s,
                                                   const float* __restrict__ d,
                                                   const unsigned* __restrict__ Hb,
                                                   const float* __restrict__ bias,
                                                   const float* __restrict__ x_prev,
                                                   float* __restrict__ x_next, int n) {
    long g = (long)blockIdx.x * 256 + threadIdx.x;
    int node = (int)(g >> 6);
    int lane = (int)(g & 63);
    if (node >= n) return;

    const int beg = rowptr[node], end = rowptr[node + 1];
    const float dn = d[node];
    const float ev_self = leaky(s[node] + dn);

    // single-pass online softmax + gather-accumulate (2 channels per lane)
    float m = ev_self;
    float l = 0.f, o0 = 0.f, o1 = 0.f;
    for (int j0 = beg; j0 < end; j0 += 64) {
        int cnt = min(64, end - j0);
        int srcv = 0;
        float ev = -INFINITY;
        if (lane < cnt) {
            srcv = col[j0 + lane];
            ev = leaky(s[srcv] + dn);
        }
        // batch max
        float bmax = ev;
#pragma unroll
        for (int off = 32; off >= 1; off >>= 1) bmax = fmaxf(bmax, __shfl_xor(bmax, off));
        float newm = fmaxf(m, bmax);
        float scale = __expf(m - newm);
        l *= scale; o0 *= scale; o1 *= scale;
        m = newm;
        float wv = (lane < cnt) ? __expf(ev - m) : 0.f;
        for (int i = 0; i < cnt; i++) {
            int src = __shfl(srcv, i);
            float w = __shfl(wv, i);
            unsigned u = Hb[(size_t)src * 64 + lane];
            l += w;
            o0 += w * bflo(u);
            o1 += w * bfhi(u);
        }
    }
    // self loop
    float wself = __expf(ev_self - m);
    l += wself;
    unsigned us = Hb[(size_t)node * 64 + lane];
    o0 += wself * bflo(us);
    o1 += wself * bfhi(us);

    // l counted each edge 64x? no: l += w once per edge iteration per lane... but every lane adds w
    // each lane accumulated the same l (all lanes add w for every edge) -> l is the true sum per lane.
    float inv = 1.f / (l + EPS_D);
    const float2 xv = *(const float2*)&x_prev[(size_t)node * CH + lane * 2];
    float b0 = bias[lane * 2], b1 = bias[lane * 2 + 1];
    float r0 = xv.x + sigm(o0 * inv + b0);
    float r1 = xv.y + sigm(o1 * inv + b1);
    *(float2*)&x_next[(size_t)node * CH + lane * 2] = make_float2(r0, r1);
}

extern "C" void kernel_launch(void* const* d_in, const int* in_sizes, int n_in,
                              void* d_out, int out_size, void* d_ws, size_t ws_size,
                              hipStream_t stream) {
    const float* x_in = (const float*)d_in[0];
    const int* EI = (const int*)d_in[1];
    const float* Ws_all = (const float*)d_in[2];
    const float* asrc_all = (const float*)d_in[3];
    const float* adst_all = (const float*)d_in[4];
    const float* bias_all = (const float*)d_in[5];
    float* out = (float*)d_out;

    const int n = in_sizes[0] / CH;        // 100000
    const int ne = in_sizes[1] / 2;        // 1600000
    const long NC = (long)n * CH;
    const int nb = (n + 1023) / 1024;

    unsigned* hb = (unsigned*)d_ws;        // NC/2 uints (NC bf16) -> occupy NC/2 words
    float* s = (float*)d_ws + NC / 2;
    float* dd = s + n;
    float* x_ws = dd + n;
    int* rowptr = (int*)(x_ws + NC);
    int* deg = rowptr + (n + 1);           // reused as scatter cursor
    int* blocksum = deg + n;
    int* blockoff = blocksum + nb;
    int* colv = blockoff + nb;

    // --- CSR build (dst-grouped) ---
    hipMemsetAsync(deg, 0, (size_t)n * sizeof(int), stream);
    deg_k<<<(ne + 255) / 256, 256, 0, stream>>>(EI, deg, ne);
    partial_scan_k<<<nb, 1024, 0, stream>>>(deg, rowptr, blocksum, n);
    blockscan_k<<<1, 64, 0, stream>>>(blocksum, blockoff, rowptr, nb, n);
    add_off_k<<<(n + 255) / 256, 256, 0, stream>>>(rowptr, blockoff, deg, n);
    scatter_k<<<(ne + 255) / 256, 256, 0, stream>>>(EI, deg, colv, ne);

    const float* xp[LAYERS] = {x_in, out, x_ws};
    float* xn[LAYERS] = {out, x_ws, out};

    for (int m = 0; m < LAYERS; m++) {
        const float* Wm = Ws_all + (size_t)m * CH * CH;
        const float* as = asrc_all + (size_t)m * CH;
        const float* ad = adst_all + (size_t)m * CH;
        const float* bm = bias_all + (size_t)m * CH;

        gemm_k<<<(n + 63) / 64, 256, 0, stream>>>(xp[m], Wm, as, ad, hb, s, dd, n);
        node_aggr_k<<<(n * 64 + 255) / 256, 256, 0, stream>>>(rowptr, colv, s, dd, hb, bm,
                                                              xp[m], xn[m], n);
    }
}

// Round 5
// 586.682 us; speedup vs baseline: 4.9262x; 1.4059x over previous
//
#include <hip/hip_runtime.h>
#include <hip/hip_bf16.h>
#include <math.h>

#define CH 128
#define LAYERS 3
#define NEG_SLOPE 0.2f
#define EPS_D 1e-16f

typedef __attribute__((ext_vector_type(8))) short bf16x8;
typedef __attribute__((ext_vector_type(4))) float f32x4;

__device__ __forceinline__ float leaky(float e) { return e > 0.f ? e : NEG_SLOPE * e; }
__device__ __forceinline__ float sigm(float x) { return 1.f / (1.f + __expf(-x)); }

__device__ __forceinline__ unsigned bf16rne(float f) {
    unsigned u = __float_as_uint(f);
    return (u + 0x7fffu + ((u >> 16) & 1u)) >> 16;
}
__device__ __forceinline__ unsigned pack2(float f0, float f1) {
    return bf16rne(f0) | (bf16rne(f1) << 16);
}
__device__ __forceinline__ float bflo(unsigned u) { return __uint_as_float(u << 16); }
__device__ __forceinline__ float bfhi(unsigned u) { return __uint_as_float(u & 0xffff0000u); }

// ---------------- CSR build -----------------------------------------------------------------
__global__ void deg_k(const int* __restrict__ EI, int* __restrict__ deg, int ne) {
    int e = blockIdx.x * 256 + threadIdx.x;
    if (e >= ne) return;
    atomicAdd(&deg[EI[ne + e]], 1);
}

__global__ __launch_bounds__(1024) void partial_scan_k(const int* __restrict__ deg,
                                                       int* __restrict__ rowptr,
                                                       int* __restrict__ blocksum, int n) {
    __shared__ int wsum[16];
    const int t = threadIdx.x;
    const int lane = t & 63, w = t >> 6;
    const int idx = blockIdx.x * 1024 + t;
    int v = (idx < n) ? deg[idx] : 0;
    int sc = v;
#pragma unroll
    for (int off = 1; off < 64; off <<= 1) {
        int x = __shfl_up(sc, off);
        if (lane >= off) sc += x;
    }
    if (lane == 63) wsum[w] = sc;
    __syncthreads();
    if (w == 0) {
        int ws = (lane < 16) ? wsum[lane] : 0;
#pragma unroll
        for (int off = 1; off < 16; off <<= 1) {
            int x = __shfl_up(ws, off);
            if (lane >= off) ws += x;
        }
        if (lane < 16) wsum[lane] = ws;
    }
    __syncthreads();
    int excl = sc - v + (w > 0 ? wsum[w - 1] : 0);
    if (idx < n) rowptr[idx] = excl;
    if (t == 1023) blocksum[blockIdx.x] = excl + v;
}

__global__ __launch_bounds__(64) void blockscan_k(const int* __restrict__ blocksum,
                                                  int* __restrict__ blockoff,
                                                  int* __restrict__ rowptr, int nb, int n) {
    const int lane = threadIdx.x;
    int carry = 0;
    for (int base = 0; base < nb; base += 64) {
        int v = (base + lane < nb) ? blocksum[base + lane] : 0;
        int sc = v;
#pragma unroll
        for (int off = 1; off < 64; off <<= 1) {
            int x = __shfl_up(sc, off);
            if (lane >= off) sc += x;
        }
        if (base + lane < nb) blockoff[base + lane] = carry + sc - v;
        carry += __shfl(sc, 63);
    }
    if (lane == 0) rowptr[n] = carry;
}

__global__ void add_off_k(int* __restrict__ rowptr, const int* __restrict__ blockoff,
                          int* __restrict__ cursor, int n) {
    int idx = blockIdx.x * 256 + threadIdx.x;
    if (idx >= n) return;
    int val = rowptr[idx] + blockoff[idx >> 10];
    rowptr[idx] = val;
    cursor[idx] = val;
}

__global__ void scatter_k(const int* __restrict__ EI, int* __restrict__ cursor,
                          int* __restrict__ col, int ne) {
    int e = blockIdx.x * 256 + threadIdx.x;
    if (e >= ne) return;
    int src = EI[e], dst = EI[ne + e];
    int pos = atomicAdd(&cursor[dst], 1);
    col[pos] = src;
}

// ---------------- MFMA GEMM: H(bf16) = X @ W, fused s = H.a_src, d = H.a_dst ----------------
// 64 nodes/block, 256 threads (4 waves). Wave: 16 rows x 128 cols = 8 tiles of 16x16, K=128.
__global__ __launch_bounds__(256) void gemm_k(const float* __restrict__ X,
                                              const float* __restrict__ Wm,
                                              const float* __restrict__ asrc,
                                              const float* __restrict__ adst,
                                              unsigned* __restrict__ Hb,
                                              float* __restrict__ s,
                                              float* __restrict__ d, int n) {
    __shared__ unsigned Wsu[128 * 67];   // bf16 [128][134] (rows padded to 134 shorts)
    __shared__ unsigned Xsu[64 * 68];    // bf16 [64][136]
    short* Ws = (short*)Wsu;
    short* Xs = (short*)Xsu;
    const int t = threadIdx.x;
    const int node0 = blockIdx.x * 64;

    // stage W -> bf16 LDS (8192 u32 words, 32/thread), coalesced float2 reads
#pragma unroll
    for (int i = 0; i < 32; i++) {
        int wd = i * 256 + t;
        int k = wd >> 6, cp = wd & 63;
        const float2 v = *(const float2*)&Wm[k * 128 + cp * 2];
        Wsu[k * 67 + cp] = pack2(v.x, v.y);
    }
    // stage X tile -> bf16 LDS (4096 words, 16/thread)
#pragma unroll
    for (int i = 0; i < 16; i++) {
        int wd = i * 256 + t;
        int r = wd >> 6, cp = wd & 63;
        int node = node0 + r;
        float2 v = make_float2(0.f, 0.f);
        if (node < n) v = *(const float2*)&X[(size_t)node * CH + cp * 2];
        Xsu[r * 68 + cp] = pack2(v.x, v.y);
    }
    __syncthreads();

    const int lane = t & 63, w = t >> 6;
    const int lr = lane & 15, lg = lane >> 4;

    f32x4 acc[8];
#pragma unroll
    for (int ct = 0; ct < 8; ct++) acc[ct] = (f32x4){0.f, 0.f, 0.f, 0.f};

#pragma unroll
    for (int kt = 0; kt < 4; kt++) {
        // A frag: row = w*16 + lr, k = kt*32 + lg*8 + j  (16B contiguous)
        bf16x8 a = *(bf16x8*)&Xs[(w * 16 + lr) * 136 + kt * 32 + lg * 8];
        const int kb = kt * 32 + lg * 8;
#pragma unroll
        for (int ct = 0; ct < 8; ct++) {
            const int cc = ct * 16 + lr;
            bf16x8 b;
#pragma unroll
            for (int j = 0; j < 8; j++) b[j] = Ws[(kb + j) * 134 + cc];
            acc[ct] = __builtin_amdgcn_mfma_f32_16x16x32_bf16(a, b, acc[ct], 0, 0, 0);
        }
    }

    // epilogue: H bf16 store + fused s,d
    float asv[8], adv[8];
#pragma unroll
    for (int ct = 0; ct < 8; ct++) { asv[ct] = asrc[ct * 16 + lr]; adv[ct] = adst[ct * 16 + lr]; }

    short* Hs = (short*)Hb;
#pragma unroll
    for (int r = 0; r < 4; r++) {
        const int row = w * 16 + lg * 4 + r;
        const int node = node0 + row;
        float ps = 0.f, pd = 0.f;
#pragma unroll
        for (int ct = 0; ct < 8; ct++) {
            float hv = acc[ct][r];
            ps += hv * asv[ct];
            pd += hv * adv[ct];
            if (node < n) Hs[(size_t)node * CH + ct * 16 + lr] = (short)bf16rne(hv);
        }
#pragma unroll
        for (int off = 8; off >= 1; off >>= 1) {
            ps += __shfl_xor(ps, off);
            pd += __shfl_xor(pd, off);
        }
        if (lr == 0 && node < n) { s[node] = ps; d[node] = pd; }
    }
}

// ---------------- per-node online-softmax + aggregation + residual (wave per node) ----------
// 4 channels/lane; two 32-lane halves each process one edge per iteration.
__global__ __launch_bounds__(256) void node_aggr_k(const int* __restrict__ rowptr,
                                                   const int* __restrict__ col,
                                                   const float* __restrict__ s,
                                                   const float* __restrict__ d,
                                                   const unsigned* __restrict__ Hb,
                                                   const float* __restrict__ bias,
                                                   const float* __restrict__ x_prev,
                                                   float* __restrict__ x_next, int n) {
    long g = (long)blockIdx.x * 256 + threadIdx.x;
    int node = (int)(g >> 6);
    int lane = (int)(g & 63);
    if (node >= n) return;
    const int half = lane >> 5, sub = lane & 31;

    const int beg = rowptr[node], end = rowptr[node + 1];
    const float dn = d[node];
    const float ev_self = leaky(s[node] + dn);

    float m = ev_self;
    float l = 0.f, o0 = 0.f, o1 = 0.f, o2 = 0.f, o3 = 0.f;

    for (int j0 = beg; j0 < end; j0 += 64) {
        int cnt = min(64, end - j0);
        int srcv = 0;
        float ev = -INFINITY;
        if (lane < cnt) {
            srcv = col[j0 + lane];
            ev = leaky(s[srcv] + dn);
        }
        float bmax = ev;
#pragma unroll
        for (int off = 32; off >= 1; off >>= 1) bmax = fmaxf(bmax, __shfl_xor(bmax, off));
        float newm = fmaxf(m, bmax);
        float scale = __expf(m - newm);
        l *= scale; o0 *= scale; o1 *= scale; o2 *= scale; o3 *= scale;
        m = newm;
        float wv = (lane < cnt) ? __expf(ev - m) : 0.f;

        for (int i = 0; i < cnt; i += 2) {
            int sA = __shfl(srcv, i);
            int sB = __shfl(srcv, min(i + 1, cnt - 1));
            float wA = __shfl(wv, i);
            float wB = (i + 1 < cnt) ? __shfl(wv, i + 1) : 0.f;
            int se = half ? sB : sA;
            float we = half ? wB : wA;
            const uint2 u = *(const uint2*)&Hb[(size_t)se * 64 + sub * 2];
            l += we;
            o0 += we * bflo(u.x);
            o1 += we * bfhi(u.x);
            o2 += we * bflo(u.y);
            o3 += we * bfhi(u.y);
        }
    }

    // merge the two halves (each channel set is duplicated across lane and lane^32)
    l += __shfl_xor(l, 32);
    o0 += __shfl_xor(o0, 32);
    o1 += __shfl_xor(o1, 32);
    o2 += __shfl_xor(o2, 32);
    o3 += __shfl_xor(o3, 32);

    // self loop (both halves compute identical values)
    float wself = __expf(ev_self - m);
    l += wself;
    const uint2 us = *(const uint2*)&Hb[(size_t)node * 64 + sub * 2];
    o0 += wself * bflo(us.x);
    o1 += wself * bfhi(us.x);
    o2 += wself * bflo(us.y);
    o3 += wself * bfhi(us.y);

    if (half == 0) {
        float inv = 1.f / (l + EPS_D);
        const float4 xv = *(const float4*)&x_prev[(size_t)node * CH + sub * 4];
        float4 r;
        r.x = xv.x + sigm(o0 * inv + bias[sub * 4 + 0]);
        r.y = xv.y + sigm(o1 * inv + bias[sub * 4 + 1]);
        r.z = xv.z + sigm(o2 * inv + bias[sub * 4 + 2]);
        r.w = xv.w + sigm(o3 * inv + bias[sub * 4 + 3]);
        *(float4*)&x_next[(size_t)node * CH + sub * 4] = r;
    }
}

extern "C" void kernel_launch(void* const* d_in, const int* in_sizes, int n_in,
                              void* d_out, int out_size, void* d_ws, size_t ws_size,
                              hipStream_t stream) {
    const float* x_in = (const float*)d_in[0];
    const int* EI = (const int*)d_in[1];
    const float* Ws_all = (const float*)d_in[2];
    const float* asrc_all = (const float*)d_in[3];
    const float* adst_all = (const float*)d_in[4];
    const float* bias_all = (const float*)d_in[5];
    float* out = (float*)d_out;

    const int n = in_sizes[0] / CH;        // 100000
    const int ne = in_sizes[1] / 2;        // 1600000
    const long NC = (long)n * CH;
    const int nb = (n + 1023) / 1024;

    unsigned* hb = (unsigned*)d_ws;        // NC bf16 = NC/2 u32
    float* s = (float*)d_ws + NC / 2;
    float* dd = s + n;
    float* x_ws = dd + n;
    int* rowptr = (int*)(x_ws + NC);
    int* deg = rowptr + (n + 1);           // reused as scatter cursor
    int* blocksum = deg + n;
    int* blockoff = blocksum + nb;
    int* colv = blockoff + nb;

    // --- CSR build (dst-grouped) ---
    hipMemsetAsync(deg, 0, (size_t)n * sizeof(int), stream);
    deg_k<<<(ne + 255) / 256, 256, 0, stream>>>(EI, deg, ne);
    partial_scan_k<<<nb, 1024, 0, stream>>>(deg, rowptr, blocksum, n);
    blockscan_k<<<1, 64, 0, stream>>>(blocksum, blockoff, rowptr, nb, n);
    add_off_k<<<(n + 255) / 256, 256, 0, stream>>>(rowptr, blockoff, deg, n);
    scatter_k<<<(ne + 255) / 256, 256, 0, stream>>>(EI, deg, colv, ne);

    const float* xp[LAYERS] = {x_in, out, x_ws};
    float* xn[LAYERS] = {out, x_ws, out};

    for (int m = 0; m < LAYERS; m++) {
        const float* Wm = Ws_all + (size_t)m * CH * CH;
        const float* as = asrc_all + (size_t)m * CH;
        const float* ad = adst_all + (size_t)m * CH;
        const float* bm = bias_all + (size_t)m * CH;

        gemm_k<<<(n + 63) / 64, 256, 0, stream>>>(xp[m], Wm, as, ad, hb, s, dd, n);
        node_aggr_k<<<(n * 64 + 255) / 256, 256, 0, stream>>>(rowptr, colv, s, dd, hb, bm,
                                                              xp[m], xn[m], n);
    }
}